// Round 1
// baseline (2188.126 us; speedup 1.0000x reference)
//
#include <hip/hip_runtime.h>
#include <cstddef>

// ---------------------------------------------------------------------------
// WTConv2d: 3-level Haar DWT + 3x3 conv per level + inverse DWT + bias.
// B=4, C=64, H=W=192 (divisible by 8 -> no padding path).
// Round 1: correct fp32 baseline. DWT/IDWT fused elementwise kernels,
// direct conv with LDS input tile, 2x2 px/thread, NCOUT couts/block.
// ---------------------------------------------------------------------------

__global__ __launch_bounds__(256) void dwt_kernel(
    const float* __restrict__ in, float* __restrict__ out,
    int B, int C, int inCperB, int H2, int W2)
{
    int idx = blockIdx.x * 256 + threadIdx.x;
    int total = B * C * H2 * W2;
    if (idx >= total) return;
    int j = idx % W2;
    int t = idx / W2;
    int i = t % H2; t /= H2;
    int c = t % C;
    int b = t / C;
    int W = 2 * W2;
    const float* p = in + ((size_t)(b * inCperB + c) * (2 * H2) + 2 * i) * W + 2 * j;
    float2 top = *(const float2*)p;
    float2 bot = *(const float2*)(p + W);
    float a = top.x, bb = top.y, cc = bot.x, dd = bot.y;
    const float s2 = 0.25f;  // DWT_SCALE^2
    float ll = s2 * (a + bb + cc + dd);
    float lh = s2 * (a + bb - cc - dd);
    float hl = s2 * (a - bb + cc - dd);
    float hh = s2 * (a - bb - cc + dd);
    size_t plane = (size_t)H2 * W2;
    size_t o = (size_t)(b * 4 * C + c) * plane + (size_t)i * W2 + j;
    out[o] = ll;
    out[o + (size_t)C * plane] = lh;
    out[o + (size_t)(2 * C) * plane] = hl;
    out[o + (size_t)(3 * C) * plane] = hh;
}

__global__ __launch_bounds__(256) void idwt_kernel(
    const float* __restrict__ ll, int llCperB,
    const float* __restrict__ hi, int hiCperB,
    float* __restrict__ out, int outCperB,
    const float* __restrict__ bias,
    int B, int C, int H2, int W2)
{
    int idx = blockIdx.x * 256 + threadIdx.x;
    int total = B * C * H2 * W2;
    if (idx >= total) return;
    int j = idx % W2;
    int t = idx / W2;
    int i = t % H2; t /= H2;
    int c = t % C;
    int b = t / C;
    size_t plane = (size_t)H2 * W2;
    size_t ij = (size_t)i * W2 + j;
    float vll = ll[(size_t)(b * llCperB + c) * plane + ij];
    const float* hb = hi + (size_t)b * hiCperB * plane;
    float vlh = hb[(size_t)(C + c) * plane + ij];
    float vhl = hb[(size_t)(2 * C + c) * plane + ij];
    float vhh = hb[(size_t)(3 * C + c) * plane + ij];
    // IDWT_SCALE^2 = 1
    float a  = vll + vlh + vhl + vhh;
    float b2 = vll + vlh - vhl - vhh;
    float c2 = vll - vlh + vhl - vhh;
    float d2 = vll - vlh - vhl + vhh;
    if (bias) {
        float bv = bias[c];
        a += bv; b2 += bv; c2 += bv; d2 += bv;
    }
    int W = 2 * W2;
    float* op = out + ((size_t)(b * outCperB + c) * (2 * H2) + 2 * i) * W + 2 * j;
    *(float2*)op = make_float2(a, b2);
    *(float2*)(op + W) = make_float2(c2, d2);
}

// Direct 3x3 conv, stride 1, pad 1 (zeros). Each thread: 2x2 pixels x NCOUT
// output channels. Input tile staged in LDS per CCHUNK input channels.
// Weights read via block-uniform addresses (expect s_load).
template <int TILE, int NCOUT, int CCHUNK>
__global__ __launch_bounds__((TILE / 2) * (TILE / 2)) void conv3x3_kernel(
    const float* __restrict__ in, const float* __restrict__ wgt,
    float* __restrict__ out, int Cin, int Cout, int HW, int tilesX)
{
    constexpr int TPB = (TILE / 2) * (TILE / 2);
    constexpr int TW = TILE + 2;
    __shared__ float s_in[CCHUNK][TW][TW];

    const int H = HW, W = HW;
    const int tid = threadIdx.x;
    const int ty0 = (blockIdx.x / tilesX) * TILE;
    const int tx0 = (blockIdx.x % tilesX) * TILE;
    const int cout0 = blockIdx.y * NCOUT;
    const int bb = blockIdx.z;

    const int tx = tid % (TILE / 2);
    const int ty = tid / (TILE / 2);

    float acc[NCOUT][4];
#pragma unroll
    for (int co = 0; co < NCOUT; ++co)
#pragma unroll
        for (int q = 0; q < 4; ++q) acc[co][q] = 0.f;

    const size_t planeHW = (size_t)H * W;
    const float* inB = in + (size_t)bb * Cin * planeHW;

    for (int c0 = 0; c0 < Cin; c0 += CCHUNK) {
        __syncthreads();
        constexpr int TOT = CCHUNK * TW * TW;
        for (int idx = tid; idx < TOT; idx += TPB) {
            int c = idx / (TW * TW);
            int rem = idx % (TW * TW);
            int r = rem / TW;
            int col = rem % TW;
            int gy = ty0 + r - 1, gx = tx0 + col - 1;
            float v = 0.f;
            if (gy >= 0 && gy < H && gx >= 0 && gx < W)
                v = inB[(size_t)(c0 + c) * planeHW + (size_t)gy * W + gx];
            s_in[c][r][col] = v;
        }
        __syncthreads();

#pragma unroll 1
        for (int c = 0; c < CCHUNK; ++c) {
            float p[4][4];
#pragma unroll
            for (int i = 0; i < 4; ++i) {
                float2 lo = *(const float2*)&s_in[c][2 * ty + i][2 * tx];
                float2 hi2 = *(const float2*)&s_in[c][2 * ty + i][2 * tx + 2];
                p[i][0] = lo.x; p[i][1] = lo.y; p[i][2] = hi2.x; p[i][3] = hi2.y;
            }
            const float* wbase = wgt + ((size_t)cout0 * Cin + (c0 + c)) * 9;
#pragma unroll
            for (int co = 0; co < NCOUT; ++co) {
                const float* w9 = wbase + (size_t)co * Cin * 9;
                float wv[9];
#pragma unroll
                for (int k = 0; k < 9; ++k) wv[k] = w9[k];
#pragma unroll
                for (int i2 = 0; i2 < 2; ++i2)
#pragma unroll
                    for (int j2 = 0; j2 < 2; ++j2) {
                        float s = acc[co][i2 * 2 + j2];
#pragma unroll
                        for (int ky = 0; ky < 3; ++ky)
#pragma unroll
                            for (int kx = 0; kx < 3; ++kx)
                                s = fmaf(p[i2 + ky][j2 + kx], wv[ky * 3 + kx], s);
                        acc[co][i2 * 2 + j2] = s;
                    }
            }
        }
    }

    const int oy = ty0 + 2 * ty;
    const int ox = tx0 + 2 * tx;
    float* outB = out + (size_t)bb * Cout * planeHW;
#pragma unroll
    for (int co = 0; co < NCOUT; ++co) {
        float* op = outB + (size_t)(cout0 + co) * planeHW;
#pragma unroll
        for (int i2 = 0; i2 < 2; ++i2) {
            int yy = oy + i2;
            if (yy >= H) continue;
#pragma unroll
            for (int j2 = 0; j2 < 2; ++j2) {
                int xx = ox + j2;
                if (xx < W) op[(size_t)yy * W + xx] = acc[co][i2 * 2 + j2];
            }
        }
    }
}

extern "C" void kernel_launch(void* const* d_in, const int* in_sizes, int n_in,
                              void* d_out, int out_size, void* d_ws, size_t ws_size,
                              hipStream_t stream)
{
    const float* x    = (const float*)d_in[0];
    const float* w0   = (const float*)d_in[1];
    const float* w1   = (const float*)d_in[2];
    const float* w2   = (const float*)d_in[3];
    const float* bias = (const float*)d_in[4];
    float* out = (float*)d_out;

    const int B = 4, C = 64;

    // workspace layout (floats)
    float* dbuf = (float*)d_ws;                       // 4*256*96*96 = 9,437,184
    const size_t dbufN = (size_t)4 * 256 * 96 * 96;
    float* y0 = dbuf + dbufN;                         // 4*256*96*96
    float* y1 = y0 + dbufN;                           // 4*256*48*48 = 2,359,296
    float* y2 = y1 + (size_t)4 * 256 * 48 * 48;       // 4*256*24*24 =   589,824
    // ll buffers alias dbuf (dbuf dead after conv2 reads it)
    float* ll1 = dbuf;                                // 4*64*48*48
    float* ll0 = dbuf + (size_t)4 * 64 * 48 * 48;     // 4*64*96*96

    // ---- forward: level 0 ----
    {
        int total = B * C * 96 * 96;
        dwt_kernel<<<(total + 255) / 256, 256, 0, stream>>>(x, dbuf, B, C, 64, 96, 96);
    }
    conv3x3_kernel<32, 16, 4><<<dim3(9, 256 / 16, B), 256, 0, stream>>>(dbuf, w0, y0, 256, 256, 96, 3);

    // ---- level 1 ----
    {
        int total = B * C * 48 * 48;
        dwt_kernel<<<(total + 255) / 256, 256, 0, stream>>>(y0, dbuf, B, C, 256, 48, 48);
    }
    conv3x3_kernel<16, 4, 4><<<dim3(9, 256 / 4, B), 64, 0, stream>>>(dbuf, w1, y1, 256, 256, 48, 3);

    // ---- level 2 ----
    {
        int total = B * C * 24 * 24;
        dwt_kernel<<<(total + 255) / 256, 256, 0, stream>>>(y1, dbuf, B, C, 256, 24, 24);
    }
    conv3x3_kernel<16, 4, 4><<<dim3(4, 256 / 4, B), 64, 0, stream>>>(dbuf, w2, y2, 256, 256, 24, 2);

    // ---- inverse ----
    {
        int total = B * C * 24 * 24;
        idwt_kernel<<<(total + 255) / 256, 256, 0, stream>>>(y2, 256, y2, 256, ll1, C, nullptr, B, C, 24, 24);
    }
    {
        int total = B * C * 48 * 48;
        idwt_kernel<<<(total + 255) / 256, 256, 0, stream>>>(ll1, C, y1, 256, ll0, C, nullptr, B, C, 48, 48);
    }
    {
        int total = B * C * 96 * 96;
        idwt_kernel<<<(total + 255) / 256, 256, 0, stream>>>(ll0, C, y0, 256, out, C, bias, B, C, 96, 96);
    }
}

// Round 2
// 499.559 us; speedup vs baseline: 4.3801x; 4.3801x over previous
//
#include <hip/hip_runtime.h>
#include <hip/hip_bf16.h>
#include <cstddef>

// ---------------------------------------------------------------------------
// WTConv2d on MI355X, round 2: bf16 MFMA implicit-GEMM convs, NHWC internal
// layout, padded activation buffers (no boundary branches), LDS-free conv.
// ---------------------------------------------------------------------------

typedef __attribute__((ext_vector_type(8))) short short8;   // 8 bf16
typedef __attribute__((ext_vector_type(4))) float f32x4;

static __device__ __forceinline__ unsigned short f2bf(float f) {
    __hip_bfloat16 h = __float2bfloat16(f);
    return *reinterpret_cast<unsigned short*>(&h);
}

// ---- weight prep: w[cout][cin][3][3] f32 -> wT[tap][cout][cin] bf16 ----
__global__ __launch_bounds__(256) void prep_w_kernel(
    const float* __restrict__ w, unsigned short* __restrict__ wT)
{
    int idx = blockIdx.x * 256 + threadIdx.x;           // 9*256*256 total
    int tap = idx >> 16;
    int r = idx & 65535;
    int co = r >> 8, ci = r & 255;
    wT[idx] = f2bf(w[(size_t)(co * 256 + ci) * 9 + tap]);
}

// ---- DWT level 0: x NCHW f32 [4][64][192][192] -> Xp bf16 padded NHWC ----
// Xp: [4][98][98][256], interior [1..96][1..96], ch = sub*64 + c
__global__ __launch_bounds__(256) void dwt0_kernel(
    const float* __restrict__ x, unsigned short* __restrict__ Xp)
{
    const int c = threadIdx.x & 63;
    const int jj = threadIdx.x >> 6;
    const int j = blockIdx.x * 4 + jj;   // 0..95
    const int i = blockIdx.y;            // 0..95
    const int b = blockIdx.z;

    const float* p = x + ((size_t)(b * 64 + c) * 192 + 2 * i) * 192 + 2 * j;
    float2 top = *(const float2*)p;
    float2 bot = *(const float2*)(p + 192);
    float a = top.x, bb = top.y, cc = bot.x, dd = bot.y;
    const float s2 = 0.25f;
    float ll = s2 * (a + bb + cc + dd);
    float lh = s2 * (a + bb - cc - dd);
    float hl = s2 * (a - bb + cc - dd);
    float hh = s2 * (a - bb - cc + dd);
    unsigned short* o = Xp + ((size_t)(b * 98 + i + 1) * 98 + j + 1) * 256 + c;
    o[0]   = f2bf(ll);
    o[64]  = f2bf(lh);
    o[128] = f2bf(hl);
    o[192] = f2bf(hh);
}

// ---- DWT mid: y NHWC f32 [4][2H2][2W2][256] (ch<64) -> padded bf16 NHWC ----
template <int H2>
__global__ __launch_bounds__(256) void dwt_mid_kernel(
    const float* __restrict__ in, unsigned short* __restrict__ Xp)
{
    constexpr int W2 = H2;
    constexpr int Hi = 2 * H2, Wi = 2 * W2;
    const int c = threadIdx.x & 63;
    const int jj = threadIdx.x >> 6;
    const int j = blockIdx.x * 4 + jj;
    const int i = blockIdx.y;
    const int b = blockIdx.z;

    const float* p = in + ((size_t)(b * Hi + 2 * i) * Wi + 2 * j) * 256 + c;
    float a  = p[0];
    float bb = p[256];
    float cc = p[(size_t)Wi * 256];
    float dd = p[(size_t)Wi * 256 + 256];
    const float s2 = 0.25f;
    float ll = s2 * (a + bb + cc + dd);
    float lh = s2 * (a + bb - cc - dd);
    float hl = s2 * (a - bb + cc - dd);
    float hh = s2 * (a - bb - cc + dd);
    unsigned short* o = Xp + ((size_t)(b * (H2 + 2) + i + 1) * (W2 + 2) + j + 1) * 256 + c;
    o[0]   = f2bf(ll);
    o[64]  = f2bf(lh);
    o[128] = f2bf(hl);
    o[192] = f2bf(hh);
}

// ---- conv: implicit GEMM, D[cout][pixel] = sum_taps W_tap * X_shift ----
// Xp: [4][H+2][W+2][256] bf16 (zero border), Wt: [9][256][256] bf16,
// Y: [4][H][W][256] f32.
// Block: 4 waves = 2M x 2N. Wave: 32 cout x 32 px.
// FRAG_ROWS=1: frag n = 1 row x 16 cols. FRAG_ROWS=2: 2 rows x 8 cols.
template <int H, int W, int FRAG_ROWS>
__global__ __launch_bounds__(256) void conv_mfma_kernel(
    const short* __restrict__ Xp, const short* __restrict__ Wt,
    float* __restrict__ Y)
{
    constexpr int FCOLS = 16 / FRAG_ROWS;
    constexpr int RS = (W + 2) * 256;             // padded row stride, elements
    constexpr int colTiles = W / FCOLS;
    constexpr int rowTiles = H / (4 * FRAG_ROWS);

    const int tid = threadIdx.x;
    const int lane = tid & 63;
    const int wid = tid >> 6;
    const int wm = wid >> 1, wn = wid & 1;

    const int nt = blockIdx.x;
    const int b = nt / (rowTiles * colTiles);
    const int rem = nt % (rowTiles * colTiles);
    const int ty = rem / colTiles, tx = rem % colTiles;
    const int gy0 = ty * 4 * FRAG_ROWS + wn * 2 * FRAG_ROWS;
    const int gx0 = tx * FCOLS;
    const int cb = blockIdx.y * 64 + wm * 32;

    const int n15 = lane & 15;
    const int kgrp = lane >> 4;               // 0..3
    const int pr = n15 / FCOLS;               // lane's row within frag
    const int pc = n15 % FCOLS;

    const short* bbase = Xp + ((size_t)(b * (H + 2) + 1 + gy0 + pr) * (W + 2)
                               + 1 + gx0 + pc) * 256 + kgrp * 8;
    const short* abase = Wt + (size_t)(cb + n15) * 256 + kgrp * 8;

    f32x4 acc[2][2] = {};

    for (int ky = 0; ky < 3; ++ky) {
        for (int kx = 0; kx < 3; ++kx) {
            const int tap = ky * 3 + kx;
            const short* aB0 = abase + (size_t)tap * 65536;
            const short* aB1 = aB0 + 16 * 256;
            const short* bB0 = bbase + (ky - 1) * RS + (kx - 1) * 256;
            const short* bB1 = bB0 + FRAG_ROWS * RS;
#pragma unroll
            for (int k = 0; k < 8; ++k) {
                short8 a0 = *(const short8*)(aB0 + k * 32);
                short8 a1 = *(const short8*)(aB1 + k * 32);
                short8 b0 = *(const short8*)(bB0 + k * 32);
                short8 b1 = *(const short8*)(bB1 + k * 32);
                acc[0][0] = __builtin_amdgcn_mfma_f32_16x16x32_bf16(a0, b0, acc[0][0], 0, 0, 0);
                acc[0][1] = __builtin_amdgcn_mfma_f32_16x16x32_bf16(a0, b1, acc[0][1], 0, 0, 0);
                acc[1][0] = __builtin_amdgcn_mfma_f32_16x16x32_bf16(a1, b0, acc[1][0], 0, 0, 0);
                acc[1][1] = __builtin_amdgcn_mfma_f32_16x16x32_bf16(a1, b1, acc[1][1], 0, 0, 0);
            }
        }
    }

    // store: D row = cout = (lane>>4)*4 + reg, col = pixel = lane&15
#pragma unroll
    for (int mf = 0; mf < 2; ++mf) {
#pragma unroll
        for (int nf = 0; nf < 2; ++nf) {
            const int gy = gy0 + nf * FRAG_ROWS + pr;
            const int gx = gx0 + pc;
            const int cout = cb + mf * 16 + kgrp * 4;
            float* op = Y + ((size_t)(b * H + gy) * W + gx) * 256 + cout;
            *(f32x4*)op = acc[mf][nf];
        }
    }
}

// ---- IDWT mid: ll (NHWC, llStride ch) + hi (NHWC 256ch, ch>=64) -> out 64ch ----
template <int H2>
__global__ __launch_bounds__(256) void idwt_mid_kernel(
    const float* __restrict__ ll, int llStride,
    const float* __restrict__ hi, float* __restrict__ out)
{
    constexpr int W2 = H2;
    const int c = threadIdx.x & 63;
    const int jj = threadIdx.x >> 6;
    const int j = blockIdx.x * 4 + jj;
    const int i = blockIdx.y;
    const int b = blockIdx.z;

    size_t pix = (size_t)(b * H2 + i) * W2 + j;
    float vll = ll[pix * llStride + c];
    const float* hp = hi + pix * 256;
    float vlh = hp[64 + c];
    float vhl = hp[128 + c];
    float vhh = hp[192 + c];
    float a  = vll + vlh + vhl + vhh;
    float b2 = vll + vlh - vhl - vhh;
    float c2 = vll - vlh + vhl - vhh;
    float d2 = vll - vlh - vhl + vhh;
    float* op = out + ((size_t)(b * 2 * H2 + 2 * i) * (2 * W2) + 2 * j) * 64 + c;
    op[0] = a;
    op[64] = b2;
    op[(size_t)(2 * W2) * 64] = c2;
    op[(size_t)(2 * W2) * 64 + 64] = d2;
}

// ---- final IDWT: ll0u [4][96][96][64] + y0 highs + bias -> out NCHW f32 ----
// LDS transpose: block = (b, 16-ch group, 8x8 ll-px tile)
__global__ __launch_bounds__(256) void idwt_final_kernel(
    const float* __restrict__ ll, const float* __restrict__ hi,
    const float* __restrict__ bias, float* __restrict__ out)
{
    __shared__ float lds[16 * 324];
    const int tt = blockIdx.x;               // 12x12 tiles
    const int tyi = tt / 12, txi = tt % 12;
    const int y0 = tyi * 8, x0 = txi * 8;
    const int cg = blockIdx.y;               // 0..3
    const int b = blockIdx.z;
    const int tid = threadIdx.x;

#pragma unroll
    for (int rep = 0; rep < 4; ++rep) {
        int idx = rep * 256 + tid;
        int c16 = idx & 15;
        int px = idx >> 4;                   // 0..63
        int pi = px >> 3, pj = px & 7;
        int c = cg * 16 + c16;
        size_t pix = (size_t)(b * 96 + y0 + pi) * 96 + x0 + pj;
        float vll = ll[pix * 64 + c];
        const float* hp = hi + pix * 256;
        float vlh = hp[64 + c];
        float vhl = hp[128 + c];
        float vhh = hp[192 + c];
        float bv = bias[c];
        float a  = vll + vlh + vhl + vhh + bv;
        float b2 = vll + vlh - vhl - vhh + bv;
        float c2 = vll - vlh + vhl - vhh + bv;
        float d2 = vll - vlh - vhl + vhh + bv;
        float* l = lds + c16 * 324 + (2 * pi) * 20 + 2 * pj;
        l[0] = a; l[1] = b2;
        l[20] = c2; l[21] = d2;
    }
    __syncthreads();

    const int c16 = tid >> 4;
    const int yy = tid & 15;
    const float* l = lds + c16 * 324 + yy * 20;
    float* op = out + ((size_t)(b * 64 + cg * 16 + c16) * 192 + tyi * 16 + yy) * 192 + txi * 16;
#pragma unroll
    for (int q = 0; q < 4; ++q)
        *(f32x4*)(op + 4 * q) = *(const f32x4*)(l + 4 * q);
}

extern "C" void kernel_launch(void* const* d_in, const int* in_sizes, int n_in,
                              void* d_out, int out_size, void* d_ws, size_t ws_size,
                              hipStream_t stream)
{
    const float* x    = (const float*)d_in[0];
    const float* w0   = (const float*)d_in[1];
    const float* w1   = (const float*)d_in[2];
    const float* w2   = (const float*)d_in[3];
    const float* bias = (const float*)d_in[4];
    float* out = (float*)d_out;

    char* ws = (char*)d_ws;
    unsigned short* wT0 = (unsigned short*)(ws + 0);          // 1,179,648 B
    unsigned short* wT1 = (unsigned short*)(ws + 1179648);
    unsigned short* wT2 = (unsigned short*)(ws + 2359296);
    unsigned short* Xp0 = (unsigned short*)(ws + 3538944);    // 19,668,992 B
    unsigned short* Xp1 = (unsigned short*)(ws + 23207936);   //  5,120,000 B
    unsigned short* Xp2 = (unsigned short*)(ws + 28327936);   //  1,384,448 B
    float* y0 = (float*)(ws + 29712384);                      // 37,748,736 B
    float* y1 = (float*)(ws + 67461120);                      //  9,437,184 B
    float* y2 = (float*)(ws + 76898304);                      //  2,359,296 B
    float* ll1u = (float*)Xp1;   // alias: Xp1 dead after conv1
    float* ll0u = (float*)Xp0;   // alias: Xp0 dead after conv0

    hipMemsetAsync(Xp0, 0, 19668992, stream);
    hipMemsetAsync(Xp1, 0, 5120000, stream);
    hipMemsetAsync(Xp2, 0, 1384448, stream);

    prep_w_kernel<<<2304, 256, 0, stream>>>(w0, wT0);
    prep_w_kernel<<<2304, 256, 0, stream>>>(w1, wT1);
    prep_w_kernel<<<2304, 256, 0, stream>>>(w2, wT2);

    dwt0_kernel<<<dim3(24, 96, 4), 256, 0, stream>>>(x, Xp0);
    conv_mfma_kernel<96, 96, 1><<<dim3(576, 4), 256, 0, stream>>>(
        (const short*)Xp0, (const short*)wT0, y0);

    dwt_mid_kernel<48><<<dim3(12, 48, 4), 256, 0, stream>>>(y0, Xp1);
    conv_mfma_kernel<48, 48, 1><<<dim3(144, 4), 256, 0, stream>>>(
        (const short*)Xp1, (const short*)wT1, y1);

    dwt_mid_kernel<24><<<dim3(6, 24, 4), 256, 0, stream>>>(y1, Xp2);
    conv_mfma_kernel<24, 24, 2><<<dim3(36, 4), 256, 0, stream>>>(
        (const short*)Xp2, (const short*)wT2, y2);

    idwt_mid_kernel<24><<<dim3(6, 24, 4), 256, 0, stream>>>(y2, 256, y2, ll1u);
    idwt_mid_kernel<48><<<dim3(12, 48, 4), 256, 0, stream>>>(ll1u, 64, y1, ll0u);
    idwt_final_kernel<<<dim3(144, 4, 4), 256, 0, stream>>>(ll0u, y0, bias, out);
}

// Round 3
// 208.385 us; speedup vs baseline: 10.5004x; 2.3973x over previous
//
#include <hip/hip_runtime.h>
#include <hip/hip_bf16.h>
#include <cstddef>

// ---------------------------------------------------------------------------
// WTConv2d on MI355X, round 3: fragment-major activation/weight layouts so
// every MFMA operand load is lane-contiguous (4x256B runs per wave-load
// instead of 16 scattered lines). LDS-free conv, LDS-transpose DWT.
//
// Xp layout (u16): [B][HP][kblk:8][g:4][WP][e:8], cin = kblk*32+g*8+e
// wT layout (u16): [tap:9][kblk:8][g:4][cout:256][e:8]
// y  layout (f32): [B][H][W][256] (NHWC)
// ---------------------------------------------------------------------------

typedef __attribute__((ext_vector_type(8))) short short8;   // 8 bf16
typedef __attribute__((ext_vector_type(4))) float f32x4;

static __device__ __forceinline__ unsigned short f2bf(float f) {
    __hip_bfloat16 h = __float2bfloat16(f);
    return *reinterpret_cast<unsigned short*>(&h);
}

// ---- weight prep: w[cout][cin][3][3] f32 -> wT[tap][kb][g][cout][e] bf16 ----
__global__ __launch_bounds__(256) void prep_w_kernel(
    const float* __restrict__ w, unsigned short* __restrict__ wT)
{
    int idx = blockIdx.x * 256 + threadIdx.x;   // ((tap*8+kb)*4+g)*256+co
    int co = idx & 255;
    int g = (idx >> 8) & 3;
    int kb = (idx >> 10) & 7;
    int tap = idx >> 13;
    int cin0 = kb * 32 + g * 8;
    unsigned short tmp[8];
#pragma unroll
    for (int e = 0; e < 8; ++e)
        tmp[e] = f2bf(w[((size_t)co * 256 + cin0 + e) * 9 + tap]);
    *(short8*)(wT + (size_t)idx * 8) = *(const short8*)tmp;
}

// ---- DWT level 0: x NCHW f32 [4][64][192][192] -> Xp0 (HP=98, WP=98) ----
__global__ __launch_bounds__(256) void dwt0_kernel(
    const float* __restrict__ x, unsigned short* __restrict__ Xp)
{
    __shared__ float lds[4 * 64 * 17];
    const int j0 = blockIdx.x * 16;
    const int i  = blockIdx.y;
    const int b  = blockIdx.z;
    const int tid = threadIdx.x;
    const int j = tid & 15;
    const int c4 = tid >> 4;
#pragma unroll
    for (int it = 0; it < 4; ++it) {
        int c = c4 + it * 16;
        const float* p = x + ((size_t)(b * 64 + c) * 192 + 2 * i) * 192 + 2 * (j0 + j);
        float2 top = *(const float2*)p;
        float2 bot = *(const float2*)(p + 192);
        float a = top.x, bb = top.y, cc = bot.x, dd = bot.y;
        const float s2 = 0.25f;
        lds[(0 * 64 + c) * 17 + j] = s2 * (a + bb + cc + dd);
        lds[(1 * 64 + c) * 17 + j] = s2 * (a + bb - cc - dd);
        lds[(2 * 64 + c) * 17 + j] = s2 * (a - bb + cc - dd);
        lds[(3 * 64 + c) * 17 + j] = s2 * (a - bb - cc + dd);
    }
    __syncthreads();
#pragma unroll
    for (int it = 0; it < 2; ++it) {
        int idx = it * 256 + tid;
        int jj = idx & 15;
        int g = (idx >> 4) & 3;
        int kb = idx >> 6;
        int sub = kb >> 1;
        int c0 = (kb & 1) * 32 + g * 8;
        unsigned short tmp[8];
#pragma unroll
        for (int e = 0; e < 8; ++e)
            tmp[e] = f2bf(lds[(sub * 64 + c0 + e) * 17 + jj]);
        size_t o = ((((size_t)(b * 98 + 1 + i) * 8 + kb) * 4 + g) * 98 + 1 + j0 + jj) * 8;
        *(short8*)(Xp + o) = *(const short8*)tmp;
    }
}

// ---- DWT mid: y NHWC f32 [4][2H2][2W2][256] (ch<64 = ll) -> Xp next level ----
template <int H2, int JB>
__global__ __launch_bounds__(256) void dwt_mid_kernel(
    const float* __restrict__ in, unsigned short* __restrict__ Xp)
{
    constexpr int W2 = H2, Wi = 2 * W2, WPn = W2 + 2, HPn = H2 + 2;
    constexpr int LS = JB + 1;
    __shared__ float lds[4 * 64 * LS];
    const int j0 = blockIdx.x * JB;
    const int i = blockIdx.y;
    const int b = blockIdx.z;
    const int tid = threadIdx.x;
    const int c = tid & 63;
    const int jq = tid >> 6;
#pragma unroll
    for (int it = 0; it < JB / 4; ++it) {
        int jl = jq + it * 4;
        int j = j0 + jl;
        const float* p = in + ((size_t)(b * 2 * H2 + 2 * i) * Wi + 2 * j) * 256 + c;
        float a  = p[0];
        float bb = p[256];
        float cc = p[(size_t)Wi * 256];
        float dd = p[(size_t)Wi * 256 + 256];
        const float s2 = 0.25f;
        lds[(0 * 64 + c) * LS + jl] = s2 * (a + bb + cc + dd);
        lds[(1 * 64 + c) * LS + jl] = s2 * (a + bb - cc - dd);
        lds[(2 * 64 + c) * LS + jl] = s2 * (a - bb + cc - dd);
        lds[(3 * 64 + c) * LS + jl] = s2 * (a - bb - cc + dd);
    }
    __syncthreads();
    constexpr int CH = 8 * 4 * JB;
#pragma unroll
    for (int it = 0; it < (CH + 255) / 256; ++it) {
        int idx = it * 256 + tid;
        if (idx < CH) {
            int jj = idx % JB;
            int g = (idx / JB) & 3;
            int kb = idx / (JB * 4);
            int sub = kb >> 1;
            int c0 = (kb & 1) * 32 + g * 8;
            unsigned short tmp[8];
#pragma unroll
            for (int e = 0; e < 8; ++e)
                tmp[e] = f2bf(lds[(sub * 64 + c0 + e) * LS + jj]);
            size_t o = ((((size_t)(b * HPn + 1 + i) * 8 + kb) * 4 + g) * WPn + 1 + j0 + jj) * 8;
            *(short8*)(Xp + o) = *(const short8*)tmp;
        }
    }
}

// ---- conv: implicit GEMM on fragment-major layout, LDS-free ----
// Block: 4 waves stacked in rows, same cout slice (A shared via L1).
// Wave: (M_FRAGS*16) couts x (NF*FROWS rows x FCOLS cols) pixels.
template <int HP, int WP, int M_FRAGS, int NF, int FCOLS>
__global__ __launch_bounds__(256) void conv_mfma_kernel(
    const short* __restrict__ Xp, const short* __restrict__ Wt,
    float* __restrict__ Y)
{
    constexpr int FROWS = 16 / FCOLS;
    constexpr int WROWS = NF * FROWS;
    constexpr int BROWS = 4 * WROWS;
    constexpr int H = HP - 2, W = WP - 2;
    constexpr int colT = W / FCOLS;
    constexpr int rowT = H / BROWS;
    constexpr size_t S_r  = (size_t)256 * WP;  // row stride (u16 elems)
    constexpr size_t S_kb = (size_t)32 * WP;
    constexpr size_t S_g  = (size_t)8 * WP;

    int bid = blockIdx.x;
    const int tx = bid % colT; bid /= colT;
    const int ty = bid % rowT; bid /= rowT;
    const int b = bid;
    const int lane = threadIdx.x & 63;
    const int wv = threadIdx.x >> 6;
    const int n15 = lane & 15;
    const int g = lane >> 4;
    const int pr = n15 / FCOLS;
    const int pc = n15 % FCOLS;
    const int cb = blockIdx.y * (M_FRAGS * 16);

    const int gy = ty * BROWS + wv * WROWS;
    const int gx = tx * FCOLS;

    f32x4 acc[M_FRAGS][NF] = {};

#pragma unroll 1
    for (int ky = 0; ky < 3; ++ky) {
        const short* Bb0 = Xp + (size_t)(b * HP + gy + pr + ky) * S_r
                              + (size_t)g * S_g + (size_t)(gx + pc) * 8;
#pragma unroll 1
        for (int kx = 0; kx < 3; ++kx) {
            const short* Ab = Wt + (size_t)(ky * 3 + kx) * 65536
                                 + (size_t)g * 2048 + (size_t)(cb + n15) * 8;
            const short* Bb = Bb0 + kx * 8;
#pragma unroll
            for (int kb = 0; kb < 8; ++kb) {
                short8 av[M_FRAGS], bv[NF];
#pragma unroll
                for (int m = 0; m < M_FRAGS; ++m)
                    av[m] = *(const short8*)(Ab + (size_t)kb * 8192 + m * 128);
#pragma unroll
                for (int n = 0; n < NF; ++n)
                    bv[n] = *(const short8*)(Bb + (size_t)kb * S_kb + (size_t)n * FROWS * S_r);
#pragma unroll
                for (int m = 0; m < M_FRAGS; ++m)
#pragma unroll
                    for (int n = 0; n < NF; ++n)
                        acc[m][n] = __builtin_amdgcn_mfma_f32_16x16x32_bf16(
                            av[m], bv[n], acc[m][n], 0, 0, 0);
            }
        }
    }

    // D: col(lane&15)=pixel, row = (lane>>4)*4 + reg = cout within 16
#pragma unroll
    for (int m = 0; m < M_FRAGS; ++m)
#pragma unroll
        for (int n = 0; n < NF; ++n) {
            int row = gy + n * FROWS + pr;
            int col = gx + pc;
            int cout = cb + m * 16 + g * 4;
            float* op = Y + ((size_t)(b * H + row) * W + col) * 256 + cout;
            *(f32x4*)op = acc[m][n];
        }
}

// ---- IDWT mid: ll (NHWC, llStride ch) + hi (NHWC 256ch) -> out 64ch NHWC ----
template <int H2>
__global__ __launch_bounds__(256) void idwt_mid_kernel(
    const float* __restrict__ ll, int llStride,
    const float* __restrict__ hi, float* __restrict__ out)
{
    constexpr int W2 = H2;
    const int c = threadIdx.x & 63;
    const int jj = threadIdx.x >> 6;
    const int j = blockIdx.x * 4 + jj;
    const int i = blockIdx.y;
    const int b = blockIdx.z;

    size_t pix = (size_t)(b * H2 + i) * W2 + j;
    float vll = ll[pix * llStride + c];
    const float* hp = hi + pix * 256;
    float vlh = hp[64 + c];
    float vhl = hp[128 + c];
    float vhh = hp[192 + c];
    float a  = vll + vlh + vhl + vhh;
    float b2 = vll + vlh - vhl - vhh;
    float c2 = vll - vlh + vhl - vhh;
    float d2 = vll - vlh - vhl + vhh;
    float* op = out + ((size_t)(b * 2 * H2 + 2 * i) * (2 * W2) + 2 * j) * 64 + c;
    op[0] = a;
    op[64] = b2;
    op[(size_t)(2 * W2) * 64] = c2;
    op[(size_t)(2 * W2) * 64 + 64] = d2;
}

// ---- final IDWT: ll0u [4][96][96][64] + y0 highs + bias -> out NCHW f32 ----
__global__ __launch_bounds__(256) void idwt_final_kernel(
    const float* __restrict__ ll, const float* __restrict__ hi,
    const float* __restrict__ bias, float* __restrict__ out)
{
    __shared__ float lds[16 * 324];
    const int tt = blockIdx.x;               // 12x12 tiles
    const int tyi = tt / 12, txi = tt % 12;
    const int y0 = tyi * 8, x0 = txi * 8;
    const int cg = blockIdx.y;               // 0..3
    const int b = blockIdx.z;
    const int tid = threadIdx.x;

#pragma unroll
    for (int rep = 0; rep < 4; ++rep) {
        int idx = rep * 256 + tid;
        int c16 = idx & 15;
        int px = idx >> 4;                   // 0..63
        int pi = px >> 3, pj = px & 7;
        int c = cg * 16 + c16;
        size_t pix = (size_t)(b * 96 + y0 + pi) * 96 + x0 + pj;
        float vll = ll[pix * 64 + c];
        const float* hp = hi + pix * 256;
        float vlh = hp[64 + c];
        float vhl = hp[128 + c];
        float vhh = hp[192 + c];
        float bv = bias[c];
        float a  = vll + vlh + vhl + vhh + bv;
        float b2 = vll + vlh - vhl - vhh + bv;
        float c2 = vll - vlh + vhl - vhh + bv;
        float d2 = vll - vlh - vhl + vhh + bv;
        float* l = lds + c16 * 324 + (2 * pi) * 20 + 2 * pj;
        l[0] = a; l[1] = b2;
        l[20] = c2; l[21] = d2;
    }
    __syncthreads();

    const int c16 = tid >> 4;
    const int yy = tid & 15;
    const float* l = lds + c16 * 324 + yy * 20;
    float* op = out + ((size_t)(b * 64 + cg * 16 + c16) * 192 + tyi * 16 + yy) * 192 + txi * 16;
#pragma unroll
    for (int q = 0; q < 4; ++q)
        *(f32x4*)(op + 4 * q) = *(const f32x4*)(l + 4 * q);
}

extern "C" void kernel_launch(void* const* d_in, const int* in_sizes, int n_in,
                              void* d_out, int out_size, void* d_ws, size_t ws_size,
                              hipStream_t stream)
{
    const float* x    = (const float*)d_in[0];
    const float* w0   = (const float*)d_in[1];
    const float* w1   = (const float*)d_in[2];
    const float* w2   = (const float*)d_in[3];
    const float* bias = (const float*)d_in[4];
    float* out = (float*)d_out;

    char* ws = (char*)d_ws;
    unsigned short* wT0 = (unsigned short*)(ws + 0);          // 1,179,648 B
    unsigned short* wT1 = (unsigned short*)(ws + 1179648);
    unsigned short* wT2 = (unsigned short*)(ws + 2359296);
    unsigned short* Xp0 = (unsigned short*)(ws + 3538944);    // 19,668,992 B
    unsigned short* Xp1 = (unsigned short*)(ws + 23207936);   //  5,120,000 B
    unsigned short* Xp2 = (unsigned short*)(ws + 28327936);   //  1,384,448 B
    float* y0 = (float*)(ws + 29712384);                      // 37,748,736 B
    float* y1 = (float*)(ws + 67461120);                      //  9,437,184 B
    float* y2 = (float*)(ws + 76898304);                      //  2,359,296 B
    float* ll1u = (float*)Xp1;   // alias: Xp1 dead after conv1
    float* ll0u = (float*)Xp0;   // alias: Xp0 dead after conv0

    hipMemsetAsync(Xp0, 0, 19668992, stream);
    hipMemsetAsync(Xp1, 0, 5120000, stream);
    hipMemsetAsync(Xp2, 0, 1384448, stream);

    prep_w_kernel<<<288, 256, 0, stream>>>(w0, wT0);
    prep_w_kernel<<<288, 256, 0, stream>>>(w1, wT1);
    prep_w_kernel<<<288, 256, 0, stream>>>(w2, wT2);

    dwt0_kernel<<<dim3(6, 96, 4), 256, 0, stream>>>(x, Xp0);
    conv_mfma_kernel<98, 98, 4, 4, 16><<<dim3(144, 4), 256, 0, stream>>>(
        (const short*)Xp0, (const short*)wT0, y0);

    dwt_mid_kernel<48, 16><<<dim3(3, 48, 4), 256, 0, stream>>>(y0, Xp1);
    conv_mfma_kernel<50, 50, 2, 4, 16><<<dim3(36, 8), 256, 0, stream>>>(
        (const short*)Xp1, (const short*)wT1, y1);

    dwt_mid_kernel<24, 12><<<dim3(2, 24, 4), 256, 0, stream>>>(y1, Xp2);
    conv_mfma_kernel<26, 26, 2, 3, 8><<<dim3(12, 8), 256, 0, stream>>>(
        (const short*)Xp2, (const short*)wT2, y2);

    idwt_mid_kernel<24><<<dim3(6, 24, 4), 256, 0, stream>>>(y2, 256, y2, ll1u);
    idwt_mid_kernel<48><<<dim3(12, 48, 4), 256, 0, stream>>>(ll1u, 64, y1, ll0u);
    idwt_final_kernel<<<dim3(144, 4, 4), 256, 0, stream>>>(ll0u, y0, bias, out);
}

// Round 4
// 192.852 us; speedup vs baseline: 11.3461x; 1.0805x over previous
//
#include <hip/hip_runtime.h>
#include <hip/hip_bf16.h>
#include <cstddef>

// ---------------------------------------------------------------------------
// WTConv2d on MI355X, round 4: fragment-major MFMA conv + register ping-pong
// prefetch (depth 1) + XCD-aware block swizzle + 2-wave blocks + launch trims.
//
// Xp layout (u16): [B][HP][kblk:8][g:4][WP][e:8], cin = kblk*32+g*8+e
// wT layout (u16): [tap:9][kblk:8][g:4][cout:256][e:8]
// y  layout (f32): [B][H][W][256] (NHWC)
// ---------------------------------------------------------------------------

typedef __attribute__((ext_vector_type(8))) short short8;   // 8 bf16
typedef __attribute__((ext_vector_type(4))) float f32x4;

static __device__ __forceinline__ unsigned short f2bf(float f) {
    __hip_bfloat16 h = __float2bfloat16(f);
    return *reinterpret_cast<unsigned short*>(&h);
}

// ---- weight prep (all 3 levels in one launch): grid (288, 3) ----
__global__ __launch_bounds__(256) void prep_w_kernel(
    const float* __restrict__ wa, const float* __restrict__ wb,
    const float* __restrict__ wc,
    unsigned short* __restrict__ ta, unsigned short* __restrict__ tb,
    unsigned short* __restrict__ tc)
{
    const float* w = (blockIdx.y == 0) ? wa : (blockIdx.y == 1) ? wb : wc;
    unsigned short* wT = (blockIdx.y == 0) ? ta : (blockIdx.y == 1) ? tb : tc;
    int idx = blockIdx.x * 256 + threadIdx.x;   // ((tap*8+kb)*4+g)*256+co
    int co = idx & 255;
    int g = (idx >> 8) & 3;
    int kb = (idx >> 10) & 7;
    int tap = idx >> 13;
    int cin0 = kb * 32 + g * 8;
    unsigned short tmp[8];
#pragma unroll
    for (int e = 0; e < 8; ++e)
        tmp[e] = f2bf(w[((size_t)co * 256 + cin0 + e) * 9 + tap]);
    *(short8*)(wT + (size_t)idx * 8) = *(const short8*)tmp;
}

// ---- zero only the pad borders of the three Xp buffers (one launch) ----
__global__ __launch_bounds__(256) void border_zero_kernel(
    unsigned short* __restrict__ p0, unsigned short* __restrict__ p1,
    unsigned short* __restrict__ p2)
{
    constexpr int N0 = 49664, N1 = 25088, N2 = 12800;   // 16B border chunks
    int idx = blockIdx.x * 256 + threadIdx.x;
    unsigned short* base; int HP, WP, rel;
    if (idx < N0)           { base = p0; HP = 98; WP = 98; rel = idx; }
    else if (idx < N0 + N1) { base = p1; HP = 50; WP = 50; rel = idx - N0; }
    else if (idx < N0 + N1 + N2) { base = p2; HP = 26; WP = 26; rel = idx - N0 - N1; }
    else return;
    int nb = 64 * WP + (HP - 2) * 64;   // border chunks per batch
    int b = rel / nb, r = rel % nb;
    int row, kg, px;
    if (r < 64 * WP) {                  // full top/bottom rows
        int rowSel = r / (32 * WP), rr = r % (32 * WP);
        kg = rr / WP; px = rr % WP; row = rowSel ? (HP - 1) : 0;
    } else {                            // left/right columns
        int r2 = r - 64 * WP;
        row = 1 + (r2 >> 6);
        int r3 = r2 & 63;
        kg = r3 >> 1; px = (r3 & 1) ? (WP - 1) : 0;
    }
    size_t o = (((size_t)(b * HP + row) * 32 + kg) * WP + px) * 8;
    short8 z = {};
    *(short8*)(base + o) = z;
}

// ---- DWT level 0: x NCHW f32 [4][64][192][192] -> Xp0 (HP=98, WP=98) ----
__global__ __launch_bounds__(256) void dwt0_kernel(
    const float* __restrict__ x, unsigned short* __restrict__ Xp)
{
    __shared__ float lds[4 * 64 * 17];
    const int j0 = blockIdx.x * 16;
    const int i  = blockIdx.y;
    const int b  = blockIdx.z;
    const int tid = threadIdx.x;
    const int j = tid & 15;
    const int c4 = tid >> 4;
#pragma unroll
    for (int it = 0; it < 4; ++it) {
        int c = c4 + it * 16;
        const float* p = x + ((size_t)(b * 64 + c) * 192 + 2 * i) * 192 + 2 * (j0 + j);
        float2 top = *(const float2*)p;
        float2 bot = *(const float2*)(p + 192);
        float a = top.x, bb = top.y, cc = bot.x, dd = bot.y;
        const float s2 = 0.25f;
        lds[(0 * 64 + c) * 17 + j] = s2 * (a + bb + cc + dd);
        lds[(1 * 64 + c) * 17 + j] = s2 * (a + bb - cc - dd);
        lds[(2 * 64 + c) * 17 + j] = s2 * (a - bb + cc - dd);
        lds[(3 * 64 + c) * 17 + j] = s2 * (a - bb - cc + dd);
    }
    __syncthreads();
#pragma unroll
    for (int it = 0; it < 2; ++it) {
        int idx = it * 256 + tid;
        int jj = idx & 15;
        int g = (idx >> 4) & 3;
        int kb = idx >> 6;
        int sub = kb >> 1;
        int c0 = (kb & 1) * 32 + g * 8;
        unsigned short tmp[8];
#pragma unroll
        for (int e = 0; e < 8; ++e)
            tmp[e] = f2bf(lds[(sub * 64 + c0 + e) * 17 + jj]);
        size_t o = ((((size_t)(b * 98 + 1 + i) * 8 + kb) * 4 + g) * 98 + 1 + j0 + jj) * 8;
        *(short8*)(Xp + o) = *(const short8*)tmp;
    }
}

// ---- DWT mid: y NHWC f32 (ch<64 = ll) -> Xp next level ----
template <int H2, int JB>
__global__ __launch_bounds__(256) void dwt_mid_kernel(
    const float* __restrict__ in, unsigned short* __restrict__ Xp)
{
    constexpr int W2 = H2, Wi = 2 * W2, WPn = W2 + 2, HPn = H2 + 2;
    constexpr int LS = JB + 1;
    __shared__ float lds[4 * 64 * LS];
    const int j0 = blockIdx.x * JB;
    const int i = blockIdx.y;
    const int b = blockIdx.z;
    const int tid = threadIdx.x;
    const int c = tid & 63;
    const int jq = tid >> 6;
#pragma unroll
    for (int it = 0; it < JB / 4; ++it) {
        int jl = jq + it * 4;
        int j = j0 + jl;
        const float* p = in + ((size_t)(b * 2 * H2 + 2 * i) * Wi + 2 * j) * 256 + c;
        float a  = p[0];
        float bb = p[256];
        float cc = p[(size_t)Wi * 256];
        float dd = p[(size_t)Wi * 256 + 256];
        const float s2 = 0.25f;
        lds[(0 * 64 + c) * LS + jl] = s2 * (a + bb + cc + dd);
        lds[(1 * 64 + c) * LS + jl] = s2 * (a + bb - cc - dd);
        lds[(2 * 64 + c) * LS + jl] = s2 * (a - bb + cc - dd);
        lds[(3 * 64 + c) * LS + jl] = s2 * (a - bb - cc + dd);
    }
    __syncthreads();
    constexpr int CH = 8 * 4 * JB;
#pragma unroll
    for (int it = 0; it < (CH + 255) / 256; ++it) {
        int idx = it * 256 + tid;
        if (idx < CH) {
            int jj = idx % JB;
            int g = (idx / JB) & 3;
            int kb = idx / (JB * 4);
            int sub = kb >> 1;
            int c0 = (kb & 1) * 32 + g * 8;
            unsigned short tmp[8];
#pragma unroll
            for (int e = 0; e < 8; ++e)
                tmp[e] = f2bf(lds[(sub * 64 + c0 + e) * LS + jj]);
            size_t o = ((((size_t)(b * HPn + 1 + i) * 8 + kb) * 4 + g) * WPn + 1 + j0 + jj) * 8;
            *(short8*)(Xp + o) = *(const short8*)tmp;
        }
    }
}

// ---- conv: implicit GEMM, LDS-free, reg ping-pong prefetch, XCD swizzle ----
// grid.x = 4*rowT*colT = 8*XCHUNK (pixel tiles), grid.y = cout slices.
template <int HP, int WP, int M_FRAGS, int NF, int FCOLS, int WAVES, int XCHUNK>
__global__ __launch_bounds__(WAVES * 64) void conv_mfma_kernel(
    const short* __restrict__ Xp, const short* __restrict__ Wt,
    float* __restrict__ Y)
{
    constexpr int FROWS = 16 / FCOLS;
    constexpr int WROWS = NF * FROWS;
    constexpr int BROWS = WAVES * WROWS;
    constexpr int H = HP - 2, W = WP - 2;
    constexpr int colT = W / FCOLS;
    constexpr int rowT = H / BROWS;
    constexpr size_t S_r  = (size_t)256 * WP;
    constexpr size_t S_kb = (size_t)32 * WP;
    constexpr size_t S_g  = (size_t)8 * WP;

    int bid = blockIdx.x;
    bid = (bid & 7) * XCHUNK + (bid >> 3);    // bijective: gridDim.x == 8*XCHUNK
    const int tx = bid % colT; bid /= colT;
    const int ty = bid % rowT; bid /= rowT;
    const int b = bid;
    const int lane = threadIdx.x & 63;
    const int wv = threadIdx.x >> 6;
    const int n15 = lane & 15;
    const int g = lane >> 4;
    const int pr = n15 / FCOLS;
    const int pc = n15 % FCOLS;
    const int cb = blockIdx.y * (M_FRAGS * 16);
    const int gy = ty * BROWS + wv * WROWS;
    const int gx = tx * FCOLS;

    const short* Abase = Wt + (size_t)g * 2048 + (size_t)(cb + n15) * 8;
    const short* Bbase = Xp + (size_t)(b * HP + gy + pr) * S_r
                            + (size_t)g * S_g + (size_t)(gx + pc) * 8;

    f32x4 acc[M_FRAGS][NF] = {};
    short8 abuf[2][M_FRAGS];
    short8 bbuf[2][NF];

    // preload (tap 0, kb 0)
#pragma unroll
    for (int m = 0; m < M_FRAGS; ++m)
        abuf[0][m] = *(const short8*)(Abase + m * 128);
#pragma unroll
    for (int n = 0; n < NF; ++n)
        bbuf[0][n] = *(const short8*)(Bbase + (size_t)n * FROWS * S_r);

#pragma unroll 1
    for (int s = 0; s < 9; ++s) {
        const int ky = s / 3;
        const int kx = s - 3 * ky;
        const int sn = (s == 8) ? 8 : s + 1;      // clamp: last prefetch redundant
        const int kyn = sn / 3;
        const int kxn = sn - 3 * kyn;
        const short* Ac = Abase + (size_t)s * 65536;
        const short* Bc = Bbase + (size_t)ky * S_r + kx * 8;
        const short* An = Abase + (size_t)sn * 65536;
        const short* Bn = Bbase + (size_t)kyn * S_r + kxn * 8;
#pragma unroll
        for (int kb = 0; kb < 8; ++kb) {
            const int cur = kb & 1, nxt = cur ^ 1;
            const short* Ap = (kb == 7) ? An : Ac;
            const short* Bp = (kb == 7) ? Bn : Bc;
            const int kbn = (kb == 7) ? 0 : kb + 1;
#pragma unroll
            for (int m = 0; m < M_FRAGS; ++m)
                abuf[nxt][m] = *(const short8*)(Ap + (size_t)kbn * 8192 + m * 128);
#pragma unroll
            for (int n = 0; n < NF; ++n)
                bbuf[nxt][n] = *(const short8*)(Bp + (size_t)kbn * S_kb
                                                + (size_t)n * FROWS * S_r);
#pragma unroll
            for (int m = 0; m < M_FRAGS; ++m)
#pragma unroll
                for (int n = 0; n < NF; ++n)
                    acc[m][n] = __builtin_amdgcn_mfma_f32_16x16x32_bf16(
                        abuf[cur][m], bbuf[cur][n], acc[m][n], 0, 0, 0);
        }
    }

    // D: col(lane&15)=pixel, row = (lane>>4)*4 + reg = cout within 16
#pragma unroll
    for (int m = 0; m < M_FRAGS; ++m)
#pragma unroll
        for (int n = 0; n < NF; ++n) {
            int row = gy + n * FROWS + pr;
            int col = gx + pc;
            int cout = cb + m * 16 + g * 4;
            float* op = Y + ((size_t)(b * H + row) * W + col) * 256 + cout;
            *(f32x4*)op = acc[m][n];
        }
}

// ---- IDWT mid: ll (NHWC, llStride ch) + hi (NHWC 256ch) -> out 64ch NHWC ----
template <int H2>
__global__ __launch_bounds__(256) void idwt_mid_kernel(
    const float* __restrict__ ll, int llStride,
    const float* __restrict__ hi, float* __restrict__ out)
{
    constexpr int W2 = H2;
    const int c = threadIdx.x & 63;
    const int jj = threadIdx.x >> 6;
    const int j = blockIdx.x * 4 + jj;
    const int i = blockIdx.y;
    const int b = blockIdx.z;

    size_t pix = (size_t)(b * H2 + i) * W2 + j;
    float vll = ll[pix * llStride + c];
    const float* hp = hi + pix * 256;
    float vlh = hp[64 + c];
    float vhl = hp[128 + c];
    float vhh = hp[192 + c];
    float a  = vll + vlh + vhl + vhh;
    float b2 = vll + vlh - vhl - vhh;
    float c2 = vll - vlh + vhl - vhh;
    float d2 = vll - vlh - vhl + vhh;
    float* op = out + ((size_t)(b * 2 * H2 + 2 * i) * (2 * W2) + 2 * j) * 64 + c;
    op[0] = a;
    op[64] = b2;
    op[(size_t)(2 * W2) * 64] = c2;
    op[(size_t)(2 * W2) * 64 + 64] = d2;
}

// ---- final IDWT: ll0u [4][96][96][64] + y0 highs + bias -> out NCHW f32 ----
__global__ __launch_bounds__(256) void idwt_final_kernel(
    const float* __restrict__ ll, const float* __restrict__ hi,
    const float* __restrict__ bias, float* __restrict__ out)
{
    __shared__ float lds[16 * 324];
    const int tt = blockIdx.x;               // 12x12 tiles
    const int tyi = tt / 12, txi = tt % 12;
    const int y0 = tyi * 8, x0 = txi * 8;
    const int cg = blockIdx.y;               // 0..3
    const int b = blockIdx.z;
    const int tid = threadIdx.x;

#pragma unroll
    for (int rep = 0; rep < 4; ++rep) {
        int idx = rep * 256 + tid;
        int c16 = idx & 15;
        int px = idx >> 4;                   // 0..63
        int pi = px >> 3, pj = px & 7;
        int c = cg * 16 + c16;
        size_t pix = (size_t)(b * 96 + y0 + pi) * 96 + x0 + pj;
        float vll = ll[pix * 64 + c];
        const float* hp = hi + pix * 256;
        float vlh = hp[64 + c];
        float vhl = hp[128 + c];
        float vhh = hp[192 + c];
        float bv = bias[c];
        float a  = vll + vlh + vhl + vhh + bv;
        float b2 = vll + vlh - vhl - vhh + bv;
        float c2 = vll - vlh + vhl - vhh + bv;
        float d2 = vll - vlh - vhl + vhh + bv;
        float* l = lds + c16 * 324 + (2 * pi) * 20 + 2 * pj;
        l[0] = a; l[1] = b2;
        l[20] = c2; l[21] = d2;
    }
    __syncthreads();

    const int c16 = tid >> 4;
    const int yy = tid & 15;
    const float* l = lds + c16 * 324 + yy * 20;
    float* op = out + ((size_t)(b * 64 + cg * 16 + c16) * 192 + tyi * 16 + yy) * 192 + txi * 16;
#pragma unroll
    for (int q = 0; q < 4; ++q)
        *(f32x4*)(op + 4 * q) = *(const f32x4*)(l + 4 * q);
}

extern "C" void kernel_launch(void* const* d_in, const int* in_sizes, int n_in,
                              void* d_out, int out_size, void* d_ws, size_t ws_size,
                              hipStream_t stream)
{
    const float* x    = (const float*)d_in[0];
    const float* w0   = (const float*)d_in[1];
    const float* w1   = (const float*)d_in[2];
    const float* w2   = (const float*)d_in[3];
    const float* bias = (const float*)d_in[4];
    float* out = (float*)d_out;

    char* ws = (char*)d_ws;
    unsigned short* wT0 = (unsigned short*)(ws + 0);          // 1,179,648 B
    unsigned short* wT1 = (unsigned short*)(ws + 1179648);
    unsigned short* wT2 = (unsigned short*)(ws + 2359296);
    unsigned short* Xp0 = (unsigned short*)(ws + 3538944);    // 19,668,992 B
    unsigned short* Xp1 = (unsigned short*)(ws + 23207936);   //  5,120,000 B
    unsigned short* Xp2 = (unsigned short*)(ws + 28327936);   //  1,384,448 B
    float* y0 = (float*)(ws + 29712384);                      // 37,748,736 B
    float* y1 = (float*)(ws + 67461120);                      //  9,437,184 B
    float* y2 = (float*)(ws + 76898304);                      //  2,359,296 B
    float* ll1u = (float*)Xp1;   // alias: Xp1 dead after conv1
    float* ll0u = (float*)Xp0;   // alias: Xp0 dead after conv0

    border_zero_kernel<<<342, 256, 0, stream>>>(Xp0, Xp1, Xp2);
    prep_w_kernel<<<dim3(288, 3), 256, 0, stream>>>(w0, w1, w2, wT0, wT1, wT2);

    dwt0_kernel<<<dim3(6, 96, 4), 256, 0, stream>>>(x, Xp0);
    // 96x96, 64co slices x4, 2-wave blocks: tiles = 4*12*6 = 288 = 8*36
    conv_mfma_kernel<98, 98, 4, 4, 16, 2, 36><<<dim3(288, 4), 128, 0, stream>>>(
        (const short*)Xp0, (const short*)wT0, y0);

    dwt_mid_kernel<48, 16><<<dim3(3, 48, 4), 256, 0, stream>>>(y0, Xp1);
    // 48x48, 32co slices x8: tiles = 4*6*3 = 72 = 8*9
    conv_mfma_kernel<50, 50, 2, 4, 16, 2, 9><<<dim3(72, 8), 128, 0, stream>>>(
        (const short*)Xp1, (const short*)wT1, y1);

    dwt_mid_kernel<24, 12><<<dim3(2, 24, 4), 256, 0, stream>>>(y1, Xp2);
    // 24x24, 32co slices x8: tiles = 4*2*3 = 24 = 8*3
    conv_mfma_kernel<26, 26, 2, 3, 8, 2, 3><<<dim3(24, 8), 128, 0, stream>>>(
        (const short*)Xp2, (const short*)wT2, y2);

    idwt_mid_kernel<24><<<dim3(6, 24, 4), 256, 0, stream>>>(y2, 256, y2, ll1u);
    idwt_mid_kernel<48><<<dim3(12, 48, 4), 256, 0, stream>>>(ll1u, 64, y1, ll0u);
    idwt_final_kernel<<<dim3(144, 4, 4), 256, 0, stream>>>(ll0u, y0, bias, out);
}